// Round 14
// baseline (200.430 us; speedup 1.0000x reference)
//
#include <hip/hip_runtime.h>
#include <hip/hip_bf16.h>
#include <stdint.h>

// LocalAttention: B=16, N=1024 (32x32 grid), C=1024, H=16, D=64.
// cvt->bf16 (fused) ; GEMM1 qkv=x@w_qkv^T (gemm_bk32, 925 TF plateau) ;
// local 3x3 window attention (4-row blocks, 4-lane tokens, all-DPP reduce,
// slot-swizzled LDS) ; GEMM2 out=attn@w_proj^T+b (930 TF). Workspace ~176 MB.
//
// GEMM plateau final: 9 structural variants land 874-930 TF; 925/930 matches
// the documented plain-HIP non-8-phase ceiling (m157: 912-948). 8-phase ports
// regressed 3x at K=1024 (16 K-tiles -> barrier overhead never amortizes).

typedef __bf16 bf16;
typedef __bf16 bf16x4_t __attribute__((ext_vector_type(4)));
typedef __bf16 bf16x8_t __attribute__((ext_vector_type(8)));
typedef float f32x4_t __attribute__((ext_vector_type(4)));

static __device__ __forceinline__ void gload_lds16(const void* g, void* l) {
  __builtin_amdgcn_global_load_lds((__attribute__((address_space(1))) void*)g,
                                   (__attribute__((address_space(3))) void*)l,
                                   16, 0, 0);
}

// raw s_barrier with compile-time memory fences (no vmcnt/lgkm drain)
static __device__ __forceinline__ void block_barrier() {
  asm volatile("" ::: "memory");
  __builtin_amdgcn_s_barrier();
  asm volatile("" ::: "memory");
}

// lane-group add via DPP quad_perm (VALU pipe -- no DS op).
// CTRL 0xB1 = quad_perm[1,0,3,2] (xor 1); 0x4E = quad_perm[2,3,0,1] (xor 2).
template<int CTRL>
static __device__ __forceinline__ float dpp_xor_add(float v) {
  int x = __builtin_amdgcn_update_dpp(0, __float_as_int(v), CTRL, 0xF, 0xF, true);
  return v + __int_as_float(x);
}

// ---------------- fused f32 -> bf16 conversion (x, w_qkv, w_proj) --------------
__global__ void cvt_all(const float* __restrict__ x, const float* __restrict__ wq,
                        const float* __restrict__ wp, bf16* __restrict__ xb,
                        bf16* __restrict__ wqb, bf16* __restrict__ wpb) {
  constexpr int NX = 4194304, NWQ = 786432;          // float4 counts
  int i = blockIdx.x * blockDim.x + threadIdx.x;     // grid exactly covers total
  const float* src; bf16* dst; int off;
  if (i < NX)            { src = x;  dst = xb;  off = i; }
  else if (i < NX + NWQ) { src = wq; dst = wqb; off = i - NX; }
  else                   { src = wp; dst = wpb; off = i - (NX + NWQ); }
  float4 v = reinterpret_cast<const float4*>(src)[off];
  bf16x4_t o;
  o[0] = (bf16)v.x; o[1] = (bf16)v.y; o[2] = (bf16)v.z; o[3] = (bf16)v.w;
  reinterpret_cast<bf16x4_t*>(dst)[off] = o;
}

// ---------------- 256x256 8-wave bf16 GEMM, C = A @ B^T, BK=32 (r6 verbatim) ---
template<int OUT_BF16>
__global__ __launch_bounds__(512, 2)
void gemm_bk32(const bf16* __restrict__ A, const bf16* __restrict__ Bm,
               void* __restrict__ Cout, const float* __restrict__ bias,
               int M, int N, int K) {
  constexpr int SLOT = 32768;                // A 16KB + B 16KB
  extern __shared__ __align__(16) char lds[];

  const int tid = threadIdx.x;
  const int w = tid >> 6, lane = tid & 63;
  const int fr = lane & 15, g = lane >> 4;
  const int wr = w >> 2, wc = w & 3;          // wave grid 2 x 4

  // T1: XCD-aware bijective swizzle (nwg % 8 == 0 for both call sites)
  const int nwg = gridDim.x * gridDim.y;
  int lid = blockIdx.y * gridDim.x + blockIdx.x;
  lid = (lid & 7) * (nwg >> 3) + (lid >> 3);
  const int bx = lid % gridDim.x, by = lid / gridDim.x;
  const int row0 = by * 256, col0 = bx * 256;

  const bf16* Ag = A + (size_t)row0 * K;
  const bf16* Bg = Bm + (size_t)col0 * K;
  const int srow = tid >> 2;                                // 0..127
  const int scol = ((tid & 3) ^ ((tid >> 3) & 3)) * 8;      // inverse-swizzled col
  const int nkt  = K >> 5;                                  // 32

  f32x4_t acc[8][4] = {};

  auto stage = [&](int kt, int slot) {       // 4 gload_lds16 per thread
    const int kb = kt << 5;
    char* sb = lds + slot * SLOT;
    gload_lds16(Ag + (size_t)(srow) * K + kb + scol,       sb + tid * 16);
    gload_lds16(Ag + (size_t)(128 + srow) * K + kb + scol, sb + 8192 + tid * 16);
    gload_lds16(Bg + (size_t)(srow) * K + kb + scol,       sb + 16384 + tid * 16);
    gload_lds16(Bg + (size_t)(128 + srow) * K + kb + scol, sb + 24576 + tid * 16);
  };

  const int uxor = ((fr >> 1) & 3) << 4;   // T2 read-side XOR (lane-constant)

  stage(0, 0);
  stage(1, 1);
  asm volatile("s_waitcnt vmcnt(4)" ::: "memory");
  block_barrier();

  for (int kt = 0; kt < nkt; ++kt) {
    const char* cA = lds + (kt & 1) * SLOT;
    const char* cB = cA + 16384;
    const bool pf = (kt + 2 < nkt);

    bf16x8_t a0[4], a1[4], b0[2], b1[2];
    auto lda = [&](bf16x8_t (&dst)[4], int q) {
#pragma unroll
      for (int i = 0; i < 4; ++i) {
        const int row = wr * 128 + (q * 4 + i) * 16 + fr;
        dst[i] = *reinterpret_cast<const bf16x8_t*>(cA + (row << 6) + ((g << 4) ^ uxor));
      }
    };
    auto ldb = [&](bf16x8_t (&dst)[2], int q) {
#pragma unroll
      for (int j = 0; j < 2; ++j) {
        const int row = wc * 64 + (q * 2 + j) * 16 + fr;
        dst[j] = *reinterpret_cast<const bf16x8_t*>(cB + (row << 6) + ((g << 4) ^ uxor));
      }
    };

    // zig-zag: each fragment read once; b0 held across the tile
    lda(a0, 0);
    ldb(b0, 0);
#pragma unroll
    for (int i = 0; i < 4; ++i)
#pragma unroll
      for (int j = 0; j < 2; ++j)
        acc[i][j] = __builtin_amdgcn_mfma_f32_16x16x32_bf16(a0[i], b0[j], acc[i][j], 0, 0, 0);
    ldb(b1, 1);
#pragma unroll
    for (int i = 0; i < 4; ++i)
#pragma unroll
      for (int j = 0; j < 2; ++j)
        acc[i][2 + j] = __builtin_amdgcn_mfma_f32_16x16x32_bf16(a0[i], b1[j], acc[i][2 + j], 0, 0, 0);
    lda(a1, 1);
#pragma unroll
    for (int i = 0; i < 4; ++i)
#pragma unroll
      for (int j = 0; j < 2; ++j)
        acc[4 + i][2 + j] = __builtin_amdgcn_mfma_f32_16x16x32_bf16(
            a1[i], b1[j], acc[4 + i][2 + j], 0, 0, 0);
#pragma unroll
    for (int i = 0; i < 4; ++i)
#pragma unroll
      for (int j = 0; j < 2; ++j)
        acc[4 + i][j] = __builtin_amdgcn_mfma_f32_16x16x32_bf16(
            a1[i], b0[j], acc[4 + i][j], 0, 0, 0);

    block_barrier();
    if (pf) stage(kt + 2, kt & 1);
    if (kt < nkt - 2) asm volatile("s_waitcnt vmcnt(4)" ::: "memory");
    else              asm volatile("s_waitcnt vmcnt(0)" ::: "memory");
    block_barrier();
  }

  // epilogue: D row = g*4+r (M), col = fr (N) per verified m89 layout
#pragma unroll
  for (int fm = 0; fm < 8; ++fm) {
    const int rbase = row0 + wr * 128 + fm * 16 + g * 4;
#pragma unroll
    for (int fn = 0; fn < 4; ++fn) {
      const int col = col0 + wc * 64 + fn * 16 + fr;
#pragma unroll
      for (int r = 0; r < 4; ++r) {
        const size_t idx = (size_t)(rbase + r) * N + col;
        if constexpr (OUT_BF16) {
          reinterpret_cast<bf16*>(Cout)[idx] = (bf16)acc[fm][fn][r];
        } else {
          reinterpret_cast<float*>(Cout)[idx] = acc[fm][fn][r] + bias[col];
        }
      }
    }
  }
}

// ---------------- local 3x3 window attention (4-row blocks, all-DPP) -----------
// qkv: [B*N][3072] bf16 (q|k|v, head h at h*64). out: [B*N][1024] bf16.
// Block = (b, h, row-quad): 128 tokens, 512 threads = 4 lanes/token x 16 dims.
// Window = 6 grid rows = 192 tokens; K/V staged to LDS (24+24 KB) with 16B-slot
// swizzle (unit = slot ^ (tokcol&7), inverse on global src, rule #21).
// Staging amplification 1.5x (r13: 2.0x). Dot reduce = 2 DPP quad_perm adds:
// zero DS shuffle ops.
__global__ __launch_bounds__(512)
void local_attn(const bf16* __restrict__ qkv, bf16* __restrict__ outp) {
  __shared__ __align__(16) char sK[24576];   // [192 tokens][128 B]
  __shared__ __align__(16) char sV[24576];

  const int tid = threadIdx.x;
  // T1: XCD swizzle (nwg = 2048): same-(b,h) blocks contiguous per XCD
  int lid = blockIdx.x;
  lid = (lid & 7) * 256 + (lid >> 3);
  const int rp = lid & 7, h = (lid >> 3) & 15, b = lid >> 7;
  const int r0 = rp * 4;

  const bf16* qkvb = qkv + (size_t)(b * 1024) * 3072 + h * 64;

  // ---- stage K/V window rows r0-1 .. r0+4 (clamped), slot-swizzled source ----
  // unit index u = p*512 + tid : row = u>>8 (0..5), tc = (u>>3)&31, slot = u&7
#pragma unroll
  for (int p = 0; p < 3; ++p) {
    const int u = p * 512 + tid;
    const int wrow = u >> 8, tc = (u >> 3) & 31, slot = u & 7;
    const int unit = slot ^ (tc & 7);
    const int jrow = min(max(r0 - 1 + wrow, 0), 31);
    const bf16* src = qkvb + (size_t)(jrow * 32 + tc) * 3072 + unit * 8;
    gload_lds16(src + 1024, sK + p * 8192 + tid * 16);
    gload_lds16(src + 2048, sV + p * 8192 + tid * 16);
  }

  // ---- q for this thread's token (overlaps staging latency) ----
  const int tok = tid >> 2, ch = tid & 3;        // token 0..127, lane-in-token
  const int row = r0 + (tok >> 5), col = tok & 31;
  const int i = row * 32 + col;
  const bf16* qp = qkvb + (size_t)i * 3072 + ch * 16;
  bf16x8_t q0 = *reinterpret_cast<const bf16x8_t*>(qp);
  bf16x8_t q1 = *reinterpret_cast<const bf16x8_t*>(qp + 8);
  float qf[16];
#pragma unroll
  for (int e = 0; e < 8; ++e) { qf[e] = (float)q0[e]; qf[8 + e] = (float)q1[e]; }

  __syncthreads();   // staging complete (drains vmcnt)

  float s[9];
#pragma unroll
  for (int t = 0; t < 9; ++t) {
    const int dr = t / 3 - 1, dc = t % 3 - 1;
    const int rr = row + dr, cc = col + dc;
    const int ccl = min(max(cc, 0), 31);
    const int wtok = ((tok >> 5) + dr + 1) * 32 + ccl;
    const int key = ccl & 7;
    const char* kb = sK + wtok * 128;
    const bf16x8_t k0 = *reinterpret_cast<const bf16x8_t*>(kb + ((ch * 2) ^ key) * 16);
    const bf16x8_t k1 = *reinterpret_cast<const bf16x8_t*>(kb + ((ch * 2 + 1) ^ key) * 16);
    float ps = 0.f;
#pragma unroll
    for (int e = 0; e < 8; ++e) ps += qf[e] * (float)k0[e];
#pragma unroll
    for (int e = 0; e < 8; ++e) ps += qf[8 + e] * (float)k1[e];
    ps = dpp_xor_add<0xB1>(ps);        // xor 1 (quad_perm, VALU)
    ps = dpp_xor_add<0x4E>(ps);        // xor 2 (quad_perm, VALU) -> full dot
    const bool valid = (rr >= 0 && rr < 32 && cc >= 0 && cc < 32);
    s[t] = ps * 0.125f + (valid ? 0.f : -1e30f);
  }

  float mx = s[0];
#pragma unroll
  for (int t = 1; t < 9; ++t) mx = fmaxf(mx, s[t]);

  float denom = 0.f, o[16] = {};
#pragma unroll
  for (int t = 0; t < 9; ++t) {
    const int dr = t / 3 - 1, dc = t % 3 - 1;
    const int ccl = min(max(col + dc, 0), 31);
    const int wtok = ((tok >> 5) + dr + 1) * 32 + ccl;
    const int key = ccl & 7;
    const float p = __expf(s[t] - mx);       // exp(-huge)=0 for invalid
    denom += p;
    const char* vb = sV + wtok * 128;
    const bf16x8_t v0 = *reinterpret_cast<const bf16x8_t*>(vb + ((ch * 2) ^ key) * 16);
    const bf16x8_t v1 = *reinterpret_cast<const bf16x8_t*>(vb + ((ch * 2 + 1) ^ key) * 16);
#pragma unroll
    for (int e = 0; e < 8; ++e) { o[e] += p * (float)v0[e]; o[8 + e] += p * (float)v1[e]; }
  }

  const float inv = 1.f / denom;
  bf16x8_t ov0, ov1;
#pragma unroll
  for (int e = 0; e < 8; ++e) {
    ov0[e] = (bf16)(o[e] * inv);
    ov1[e] = (bf16)(o[8 + e] * inv);
  }
  bf16* op = outp + (size_t)(b * 1024 + i) * 1024 + h * 64 + ch * 16;
  *reinterpret_cast<bf16x8_t*>(op) = ov0;
  *reinterpret_cast<bf16x8_t*>(op + 8) = ov1;
}

extern "C" void kernel_launch(void* const* d_in, const int* in_sizes, int n_in,
                              void* d_out, int out_size, void* d_ws, size_t ws_size,
                              hipStream_t stream) {
  const float* x      = (const float*)d_in[0];
  const float* w_qkv  = (const float*)d_in[1];
  const float* w_proj = (const float*)d_in[2];
  const float* b_proj = (const float*)d_in[3];
  float* out = (float*)d_out;

  const size_t nx   = (size_t)16384 * 1024;
  const size_t nwq  = (size_t)3072 * 1024;
  const size_t nwp  = (size_t)1024 * 1024;
  const size_t nqkv = (size_t)16384 * 3072;

  bf16* x_bf  = (bf16*)d_ws;
  bf16* wq_bf = x_bf + nx;
  bf16* wp_bf = wq_bf + nwq;
  bf16* qkv   = wp_bf + nwp;
  bf16* attn  = qkv + nqkv;

  (void)hipFuncSetAttribute((const void*)&gemm_bk32<1>,
                            hipFuncAttributeMaxDynamicSharedMemorySize, 65536);
  (void)hipFuncSetAttribute((const void*)&gemm_bk32<0>,
                            hipFuncAttributeMaxDynamicSharedMemorySize, 65536);

  // fused cvt: (nx+nwq+nwp)/4 float4s = 5242880 -> 20480 blocks x 256
  cvt_all<<<20480, 256, 0, stream>>>(x, w_qkv, w_proj, x_bf, wq_bf, wp_bf);

  // qkv = x @ w_qkv^T : M=16384, N=3072, K=1024 ; grid 12x64=768 (%8==0)
  gemm_bk32<1><<<dim3(3072 / 256, 16384 / 256), 512, 65536, stream>>>(
      x_bf, wq_bf, qkv, nullptr, 16384, 3072, 1024);

  // local window attention: 2048 blocks x 512 thr (one (b,h,row-quad)/block)
  local_attn<<<2048, 512, 0, stream>>>(qkv, attn);

  // out = attn @ w_proj^T + b : M=16384, N=1024, K=1024 ; grid 4x64=256 (%8==0)
  gemm_bk32<0><<<dim3(1024 / 256, 16384 / 256), 512, 65536, stream>>>(
      attn, wp_bf, out, b_proj, 16384, 1024, 1024);
}

// Round 15
// 196.831 us; speedup vs baseline: 1.0183x; 1.0183x over previous
//
#include <hip/hip_runtime.h>
#include <hip/hip_bf16.h>
#include <stdint.h>

// LocalAttention: B=16, N=1024 (32x32 grid), C=1024, H=16, D=64.
// cvt->bf16 (fused) ; GEMM1 qkv=x@w_qkv^T (gemm_bk32, 925 TF plateau) ;
// local 3x3 window attention (2-row blocks, 4-lane tokens, all-DPP reduce,
// slot-swizzled LDS -- r13 verbatim, best measured) ;
// GEMM2 out=attn@w_proj^T+b (930 TF). Workspace ~176 MB.
//
// FINAL ASSEMBLY (r13 config): r14's 4-row attn block regressed (+4us: 8-wave
// convoy at the staging barrier outweighed the 1.5x-vs-2.0x staging saving).
// GEMM plateau final: 9 structural variants land 874-930 TF; 925/930 matches
// the documented plain-HIP non-8-phase ceiling (m157: 912-948). 8-phase ports
// regressed 3x at K=1024 (16 K-tiles -> barrier overhead never amortizes).

typedef __bf16 bf16;
typedef __bf16 bf16x4_t __attribute__((ext_vector_type(4)));
typedef __bf16 bf16x8_t __attribute__((ext_vector_type(8)));
typedef float f32x4_t __attribute__((ext_vector_type(4)));

static __device__ __forceinline__ void gload_lds16(const void* g, void* l) {
  __builtin_amdgcn_global_load_lds((__attribute__((address_space(1))) void*)g,
                                   (__attribute__((address_space(3))) void*)l,
                                   16, 0, 0);
}

// raw s_barrier with compile-time memory fences (no vmcnt/lgkm drain)
static __device__ __forceinline__ void block_barrier() {
  asm volatile("" ::: "memory");
  __builtin_amdgcn_s_barrier();
  asm volatile("" ::: "memory");
}

// lane-group add via DPP quad_perm (VALU pipe -- no DS op).
// CTRL 0xB1 = quad_perm[1,0,3,2] (xor 1); 0x4E = quad_perm[2,3,0,1] (xor 2).
template<int CTRL>
static __device__ __forceinline__ float dpp_xor_add(float v) {
  int x = __builtin_amdgcn_update_dpp(0, __float_as_int(v), CTRL, 0xF, 0xF, true);
  return v + __int_as_float(x);
}

// ---------------- fused f32 -> bf16 conversion (x, w_qkv, w_proj) --------------
__global__ void cvt_all(const float* __restrict__ x, const float* __restrict__ wq,
                        const float* __restrict__ wp, bf16* __restrict__ xb,
                        bf16* __restrict__ wqb, bf16* __restrict__ wpb) {
  constexpr int NX = 4194304, NWQ = 786432;          // float4 counts
  int i = blockIdx.x * blockDim.x + threadIdx.x;     // grid exactly covers total
  const float* src; bf16* dst; int off;
  if (i < NX)            { src = x;  dst = xb;  off = i; }
  else if (i < NX + NWQ) { src = wq; dst = wqb; off = i - NX; }
  else                   { src = wp; dst = wpb; off = i - (NX + NWQ); }
  float4 v = reinterpret_cast<const float4*>(src)[off];
  bf16x4_t o;
  o[0] = (bf16)v.x; o[1] = (bf16)v.y; o[2] = (bf16)v.z; o[3] = (bf16)v.w;
  reinterpret_cast<bf16x4_t*>(dst)[off] = o;
}

// ---------------- 256x256 8-wave bf16 GEMM, C = A @ B^T, BK=32 (r6 verbatim) ---
template<int OUT_BF16>
__global__ __launch_bounds__(512, 2)
void gemm_bk32(const bf16* __restrict__ A, const bf16* __restrict__ Bm,
               void* __restrict__ Cout, const float* __restrict__ bias,
               int M, int N, int K) {
  constexpr int SLOT = 32768;                // A 16KB + B 16KB
  extern __shared__ __align__(16) char lds[];

  const int tid = threadIdx.x;
  const int w = tid >> 6, lane = tid & 63;
  const int fr = lane & 15, g = lane >> 4;
  const int wr = w >> 2, wc = w & 3;          // wave grid 2 x 4

  // T1: XCD-aware bijective swizzle (nwg % 8 == 0 for both call sites)
  const int nwg = gridDim.x * gridDim.y;
  int lid = blockIdx.y * gridDim.x + blockIdx.x;
  lid = (lid & 7) * (nwg >> 3) + (lid >> 3);
  const int bx = lid % gridDim.x, by = lid / gridDim.x;
  const int row0 = by * 256, col0 = bx * 256;

  const bf16* Ag = A + (size_t)row0 * K;
  const bf16* Bg = Bm + (size_t)col0 * K;
  const int srow = tid >> 2;                                // 0..127
  const int scol = ((tid & 3) ^ ((tid >> 3) & 3)) * 8;      // inverse-swizzled col
  const int nkt  = K >> 5;                                  // 32

  f32x4_t acc[8][4] = {};

  auto stage = [&](int kt, int slot) {       // 4 gload_lds16 per thread
    const int kb = kt << 5;
    char* sb = lds + slot * SLOT;
    gload_lds16(Ag + (size_t)(srow) * K + kb + scol,       sb + tid * 16);
    gload_lds16(Ag + (size_t)(128 + srow) * K + kb + scol, sb + 8192 + tid * 16);
    gload_lds16(Bg + (size_t)(srow) * K + kb + scol,       sb + 16384 + tid * 16);
    gload_lds16(Bg + (size_t)(128 + srow) * K + kb + scol, sb + 24576 + tid * 16);
  };

  const int uxor = ((fr >> 1) & 3) << 4;   // T2 read-side XOR (lane-constant)

  stage(0, 0);
  stage(1, 1);
  asm volatile("s_waitcnt vmcnt(4)" ::: "memory");
  block_barrier();

  for (int kt = 0; kt < nkt; ++kt) {
    const char* cA = lds + (kt & 1) * SLOT;
    const char* cB = cA + 16384;
    const bool pf = (kt + 2 < nkt);

    bf16x8_t a0[4], a1[4], b0[2], b1[2];
    auto lda = [&](bf16x8_t (&dst)[4], int q) {
#pragma unroll
      for (int i = 0; i < 4; ++i) {
        const int row = wr * 128 + (q * 4 + i) * 16 + fr;
        dst[i] = *reinterpret_cast<const bf16x8_t*>(cA + (row << 6) + ((g << 4) ^ uxor));
      }
    };
    auto ldb = [&](bf16x8_t (&dst)[2], int q) {
#pragma unroll
      for (int j = 0; j < 2; ++j) {
        const int row = wc * 64 + (q * 2 + j) * 16 + fr;
        dst[j] = *reinterpret_cast<const bf16x8_t*>(cB + (row << 6) + ((g << 4) ^ uxor));
      }
    };

    // zig-zag: each fragment read once; b0 held across the tile
    lda(a0, 0);
    ldb(b0, 0);
#pragma unroll
    for (int i = 0; i < 4; ++i)
#pragma unroll
      for (int j = 0; j < 2; ++j)
        acc[i][j] = __builtin_amdgcn_mfma_f32_16x16x32_bf16(a0[i], b0[j], acc[i][j], 0, 0, 0);
    ldb(b1, 1);
#pragma unroll
    for (int i = 0; i < 4; ++i)
#pragma unroll
      for (int j = 0; j < 2; ++j)
        acc[i][2 + j] = __builtin_amdgcn_mfma_f32_16x16x32_bf16(a0[i], b1[j], acc[i][2 + j], 0, 0, 0);
    lda(a1, 1);
#pragma unroll
    for (int i = 0; i < 4; ++i)
#pragma unroll
      for (int j = 0; j < 2; ++j)
        acc[4 + i][2 + j] = __builtin_amdgcn_mfma_f32_16x16x32_bf16(
            a1[i], b1[j], acc[4 + i][2 + j], 0, 0, 0);
#pragma unroll
    for (int i = 0; i < 4; ++i)
#pragma unroll
      for (int j = 0; j < 2; ++j)
        acc[4 + i][j] = __builtin_amdgcn_mfma_f32_16x16x32_bf16(
            a1[i], b0[j], acc[4 + i][j], 0, 0, 0);

    block_barrier();
    if (pf) stage(kt + 2, kt & 1);
    if (kt < nkt - 2) asm volatile("s_waitcnt vmcnt(4)" ::: "memory");
    else              asm volatile("s_waitcnt vmcnt(0)" ::: "memory");
    block_barrier();
  }

  // epilogue: D row = g*4+r (M), col = fr (N) per verified m89 layout
#pragma unroll
  for (int fm = 0; fm < 8; ++fm) {
    const int rbase = row0 + wr * 128 + fm * 16 + g * 4;
#pragma unroll
    for (int fn = 0; fn < 4; ++fn) {
      const int col = col0 + wc * 64 + fn * 16 + fr;
#pragma unroll
      for (int r = 0; r < 4; ++r) {
        const size_t idx = (size_t)(rbase + r) * N + col;
        if constexpr (OUT_BF16) {
          reinterpret_cast<bf16*>(Cout)[idx] = (bf16)acc[fm][fn][r];
        } else {
          reinterpret_cast<float*>(Cout)[idx] = acc[fm][fn][r] + bias[col];
        }
      }
    }
  }
}

// ---------------- local 3x3 window attention (2-row blocks, all-DPP) -----------
// qkv: [B*N][3072] bf16 (q|k|v, head h at h*64). out: [B*N][1024] bf16.
// Block = (b, h, row-pair): 64 tokens, 256 threads = 4 lanes/token x 16 dims.
// Window = 4 grid rows = 128 tokens; K/V staged to LDS (16+16 KB) with 16B-slot
// swizzle (unit = slot ^ (tokcol&7), inverse on global src, rule #21).
// Dot reduce = 2 DPP quad_perm adds: ZERO DS shuffle ops in the whole kernel.
__global__ __launch_bounds__(256)
void local_attn(const bf16* __restrict__ qkv, bf16* __restrict__ outp) {
  __shared__ __align__(16) char sK[16384];   // [128 tokens][128 B]
  __shared__ __align__(16) char sV[16384];

  const int tid = threadIdx.x;
  // T1: XCD swizzle (nwg = 4096): same-(b,h) row-pair blocks contiguous per XCD
  int lid = blockIdx.x;
  lid = (lid & 7) * 512 + (lid >> 3);
  const int rp = lid & 15, h = (lid >> 4) & 15, b = lid >> 8;
  const int r0 = rp * 2;

  const bf16* qkvb = qkv + (size_t)(b * 1024) * 3072 + h * 64;

  // ---- stage K/V window rows r0-1 .. r0+2 (clamped), slot-swizzled source ----
  const int tc = tid >> 3;            // token column 0..31
  const int slot = tid & 7;           // LDS 16B-slot within token row
  const int unit = slot ^ (tc & 7);   // global 16B-unit (inverse swizzle)
#pragma unroll
  for (int p = 0; p < 4; ++p) {
    const int jrow = min(max(r0 - 1 + p, 0), 31);
    const bf16* src = qkvb + (size_t)(jrow * 32 + tc) * 3072 + unit * 8;
    gload_lds16(src + 1024, sK + p * 4096 + tid * 16);
    gload_lds16(src + 2048, sV + p * 4096 + tid * 16);
  }

  // ---- q for this thread's token (overlaps staging latency) ----
  const int tok = tid >> 2, ch = tid & 3;        // token 0..63, lane-in-token
  const int row = r0 + (tok >> 5), col = tok & 31;
  const int i = row * 32 + col;
  const bf16* qp = qkvb + (size_t)i * 3072 + ch * 16;
  bf16x8_t q0 = *reinterpret_cast<const bf16x8_t*>(qp);
  bf16x8_t q1 = *reinterpret_cast<const bf16x8_t*>(qp + 8);
  float qf[16];
#pragma unroll
  for (int e = 0; e < 8; ++e) { qf[e] = (float)q0[e]; qf[8 + e] = (float)q1[e]; }

  __syncthreads();   // staging complete (drains vmcnt)

  float s[9];
#pragma unroll
  for (int t = 0; t < 9; ++t) {
    const int dr = t / 3 - 1, dc = t % 3 - 1;
    const int rr = row + dr, cc = col + dc;
    const int ccl = min(max(cc, 0), 31);
    const int wtok = ((tok >> 5) + dr + 1) * 32 + ccl;
    const int key = ccl & 7;
    const char* kb = sK + wtok * 128;
    const bf16x8_t k0 = *reinterpret_cast<const bf16x8_t*>(kb + ((ch * 2) ^ key) * 16);
    const bf16x8_t k1 = *reinterpret_cast<const bf16x8_t*>(kb + ((ch * 2 + 1) ^ key) * 16);
    float ps = 0.f;
#pragma unroll
    for (int e = 0; e < 8; ++e) ps += qf[e] * (float)k0[e];
#pragma unroll
    for (int e = 0; e < 8; ++e) ps += qf[8 + e] * (float)k1[e];
    ps = dpp_xor_add<0xB1>(ps);        // xor 1 (quad_perm, VALU)
    ps = dpp_xor_add<0x4E>(ps);        // xor 2 (quad_perm, VALU) -> full dot
    const bool valid = (rr >= 0 && rr < 32 && cc >= 0 && cc < 32);
    s[t] = ps * 0.125f + (valid ? 0.f : -1e30f);
  }

  float mx = s[0];
#pragma unroll
  for (int t = 1; t < 9; ++t) mx = fmaxf(mx, s[t]);

  float denom = 0.f, o[16] = {};
#pragma unroll
  for (int t = 0; t < 9; ++t) {
    const int dr = t / 3 - 1, dc = t % 3 - 1;
    const int ccl = min(max(col + dc, 0), 31);
    const int wtok = ((tok >> 5) + dr + 1) * 32 + ccl;
    const int key = ccl & 7;
    const float p = __expf(s[t] - mx);       // exp(-huge)=0 for invalid
    denom += p;
    const char* vb = sV + wtok * 128;
    const bf16x8_t v0 = *reinterpret_cast<const bf16x8_t*>(vb + ((ch * 2) ^ key) * 16);
    const bf16x8_t v1 = *reinterpret_cast<const bf16x8_t*>(vb + ((ch * 2 + 1) ^ key) * 16);
#pragma unroll
    for (int e = 0; e < 8; ++e) { o[e] += p * (float)v0[e]; o[8 + e] += p * (float)v1[e]; }
  }

  const float inv = 1.f / denom;
  bf16x8_t ov0, ov1;
#pragma unroll
  for (int e = 0; e < 8; ++e) {
    ov0[e] = (bf16)(o[e] * inv);
    ov1[e] = (bf16)(o[8 + e] * inv);
  }
  bf16* op = outp + (size_t)(b * 1024 + i) * 1024 + h * 64 + ch * 16;
  *reinterpret_cast<bf16x8_t*>(op) = ov0;
  *reinterpret_cast<bf16x8_t*>(op + 8) = ov1;
}

extern "C" void kernel_launch(void* const* d_in, const int* in_sizes, int n_in,
                              void* d_out, int out_size, void* d_ws, size_t ws_size,
                              hipStream_t stream) {
  const float* x      = (const float*)d_in[0];
  const float* w_qkv  = (const float*)d_in[1];
  const float* w_proj = (const float*)d_in[2];
  const float* b_proj = (const float*)d_in[3];
  float* out = (float*)d_out;

  const size_t nx   = (size_t)16384 * 1024;
  const size_t nwq  = (size_t)3072 * 1024;
  const size_t nwp  = (size_t)1024 * 1024;
  const size_t nqkv = (size_t)16384 * 3072;

  bf16* x_bf  = (bf16*)d_ws;
  bf16* wq_bf = x_bf + nx;
  bf16* wp_bf = wq_bf + nwq;
  bf16* qkv   = wp_bf + nwp;
  bf16* attn  = qkv + nqkv;

  (void)hipFuncSetAttribute((const void*)&gemm_bk32<1>,
                            hipFuncAttributeMaxDynamicSharedMemorySize, 65536);
  (void)hipFuncSetAttribute((const void*)&gemm_bk32<0>,
                            hipFuncAttributeMaxDynamicSharedMemorySize, 65536);

  // fused cvt: (nx+nwq+nwp)/4 float4s = 5242880 -> 20480 blocks x 256
  cvt_all<<<20480, 256, 0, stream>>>(x, w_qkv, w_proj, x_bf, wq_bf, wp_bf);

  // qkv = x @ w_qkv^T : M=16384, N=3072, K=1024 ; grid 12x64=768 (%8==0)
  gemm_bk32<1><<<dim3(3072 / 256, 16384 / 256), 512, 65536, stream>>>(
      x_bf, wq_bf, qkv, nullptr, 16384, 3072, 1024);

  // local window attention: 4096 blocks x 256 thr (one (b,h,row-pair)/block)
  local_attn<<<4096, 256, 0, stream>>>(qkv, attn);

  // out = attn @ w_proj^T + b : M=16384, N=1024, K=1024 ; grid 4x64=256 (%8==0)
  gemm_bk32<0><<<dim3(1024 / 256, 16384 / 256), 512, 65536, stream>>>(
      attn, wp_bf, out, b_proj, 16384, 1024, 1024);
}